// Round 23
// baseline (49.313 us; speedup 1.0000x reference)
//
#include <hip/hip_runtime.h>

namespace {
constexpr int kNP = 8, kNR = 12;
constexpr int kRelCell = 288;          // NP*K*NR floats per cell (1152 B)
constexpr int kH = 64, kNOUT = 64;
constexpr int CELLS = 2;               // cells per wave
constexpr int WAVES = 8;               // 512-thread blocks
constexpr int WT_LD = 65;              // padded: conflict-free
}

typedef float v2f __attribute__((ext_vector_type(2)));

__device__ __forceinline__ float readlane_f(float v, int l) {
    union { float f; int i; } u; u.f = v;
    u.i = __builtin_amdgcn_readlane(u.i, l);
    return u.f;
}

// DPP add step on the VALU pipe; invalid source lanes contribute 0.
template<int CTRL>
__device__ __forceinline__ float dpp_add(float x) {
    int y = __builtin_amdgcn_update_dpp(0, __float_as_int(x), CTRL, 0xf, 0xf, true);
    return x + __int_as_float(y);
}
// 64-lane sum (no DS ops); lane 63 holds the total.
__device__ __forceinline__ float wave_sum63(float x) {
    x = dpp_add<0x111>(x);  // row_shr:1
    x = dpp_add<0x112>(x);  // row_shr:2
    x = dpp_add<0x114>(x);  // row_shr:4
    x = dpp_add<0x118>(x);  // row_shr:8
    x = dpp_add<0x142>(x);  // row_bcast:15
    x = dpp_add<0x143>(x);  // row_bcast:31
    return x;
}

// Load one 288-float cell into wave registers, coalesced: pfa (float4 at
// lane*4) covers floats 0..255; pfb (224+lane) covers 224..287. These regs
// serve BOTH as L2-warming prefetch and as the readlane-path operands.
__device__ __forceinline__ void load_cell(const float* cb, int lane,
                                          float4* a, float* b) {
    *a = *(const float4*)(cb + lane * 4);
    *b = cb[224 + lane];
}

// Broadcast rel[idx] (idx compile-time constant after unroll) from the wave's
// own registers via v_readlane -- no memory access, no drains. [r20-verified]
__device__ __forceinline__ float get_rel(const float4 pfa, const float pfb, int idx) {
    if (idx >= 256) return readlane_f(pfb, idx - 224);
    const int c = idx & 3;
    const float v = (c == 0) ? pfa.x : (c == 1) ? pfa.y : (c == 2) ? pfa.z : pfa.w;
    return readlane_f(v, idx >> 2);
}

// One cell: p-rows 0..3 via wave-uniform SCALAR loads (packed v_pk_fma_f32,
// r22 path -- 2 drain batches instead of 4); p-rows 4..7 via v_readlane from
// the cell's own prefetch registers (pure VALU, fills the drain shadows).
// wz2 pre-scaled by log2(e); raw v_exp_f32, no max subtraction, v_rcp.
__device__ __forceinline__ float cell_z(const float* __restrict__ cb,
                                        const float4 pfa, const float pfb,
                                        const v2f* __restrict__ dreg2,
                                        float sv_i, float wz2) {
    float zj[kNP], la[kNP];
#pragma unroll
    for (int h = 0; h < 4; ++h) {
        {   // scalar-path row p = h (packed pairs)
            const v2f* r2 = (const v2f*)(cb + h * 36);
            v2f a0 = {0.f, 0.f}, a1 = {0.f, 0.f}, a2 = {0.f, 0.f};
#pragma unroll
            for (int rr = 0; rr < 6; ++rr) {
                a0 = __builtin_elementwise_fma(r2[rr],      dreg2[rr], a0);
                a1 = __builtin_elementwise_fma(r2[6 + rr],  dreg2[rr], a1);
                a2 = __builtin_elementwise_fma(r2[12 + rr], dreg2[rr], a2);
            }
            const float d0 = a0.x + a0.y;
            const float d1 = a1.x + a1.y;
            const float d2 = a2.x + a2.y;
            const float z = d0 * d1 * d2 * sv_i;
            zj[h] = z;
            la[h] = z * wz2;
        }
        {   // readlane-path row p = h + 4 (floats 144..287, all register-held)
            const int base = (h + 4) * 36;
            float d0 = 0.f, d1 = 0.f, d2 = 0.f;
#pragma unroll
            for (int r = 0; r < kNR; ++r) {
                const float dr = dreg2[r >> 1][r & 1];
                d0 = fmaf(get_rel(pfa, pfb, base + r),      dr, d0);
                d1 = fmaf(get_rel(pfa, pfb, base + 12 + r), dr, d1);
                d2 = fmaf(get_rel(pfa, pfb, base + 24 + r), dr, d2);
            }
            const float z = d0 * d1 * d2 * sv_i;
            zj[h + 4] = z;
            la[h + 4] = z * wz2;
        }
    }
#pragma unroll
    for (int p = 0; p < kNP; ++p) la[p] = wave_sum63(la[p]);
    float esum = 0.f, zd = 0.f;
#pragma unroll
    for (int p = 0; p < kNP; ++p) {
        const float e = __builtin_amdgcn_exp2f(readlane_f(la[p], 63));
        esum += e;
        zd = fmaf(e, zj[p], zd);
    }
    return zd * __builtin_amdgcn_rcpf(esum);
}

// grid: 128 (b,v) x 16 f = 2048 blocks of 512 threads (8 waves); wave w ->
// t = 2w..2w+1 (r22 champion geometry). Changes: (1) per-cell hybrid
// scalar/readlane split (see cell_z); (2) separate 2 KB redbuf -> barrier B2
// removed (one less rendezvous before the stall region). LDS 22 KB.
__global__ __launch_bounds__(512, 4) void gal_kernel(
    const float* __restrict__ rel,      // (BS,NV,MF,MT,NP,K,NR)
    const float* __restrict__ se,       // (BS,NV,MT,MF,H)
    const float* __restrict__ s,        // unused (cancels in softmax)
    const float* __restrict__ Wstack,   // (NR,H,H)
    const float* __restrict__ lin_w,    // (1,H+NOUT)
    const float* __restrict__ lin_b,    // unused (cancels)
    const float* __restrict__ out_w,    // (NOUT,H)
    const float* __restrict__ out_b,    // (NOUT,)
    float* __restrict__ out)            // (BS,NV,NOUT)
{
    __shared__ __align__(16) float wT[kH * WT_LD];     // 16.25 KB
    __shared__ __align__(16) float dshare[kNR * kH];   // 3 KB diag
    __shared__ __align__(16) float redbuf[WAVES * 64]; // 2 KB

    const int tid  = (int)threadIdx.x;
    const int lane = tid & 63;
    const int w    = __builtin_amdgcn_readfirstlane(tid >> 6);  // uniform wave id 0..7

    const int bv = (int)blockIdx.x >> 4;   // 0..127
    const int f  = (int)blockIdx.x & 15;
    const int t0 = w * CELLS;

    const float* relbase = rel + ((size_t)((bv * 16 + f) * 16) + t0) * kRelCell;

    // load both cells into registers immediately (coalesced; L2-warm + operands)
    float4 pfa0, pfa1; float pfb0, pfb1;
    load_cell(relbase,            lane, &pfa0, &pfb0);
    load_cell(relbase + kRelCell, lane, &pfa1, &pfb1);

    // out_w (o,d) -> wT[d*65+o]; stride-65 writes -> distinct banks
    for (int i = tid; i < kH * kNOUT; i += 512) {
        const int o = i >> 6, d = i & 63;
        wT[d * WT_LD + o] = out_w[i];
    }
    // diag gather (stride-65 in Wstack) once per block
    for (int i = tid; i < kNR * kH; i += 512) {
        const int r = i >> 6, d = i & 63;
        dshare[i] = Wstack[r * kH * kH + d * (kH + 1)];
    }

    const float wz2 = lin_w[kNOUT + lane] * 1.44269504088896340736f;  // log2(e)
    const float ob = out_b[lane];   // lane = o in epilogue
    const float* sep = se + ((size_t)(bv * 16 + t0) * 16 + f) * kH + lane;
    float sev[CELLS];
#pragma unroll
    for (int i = 0; i < CELLS; ++i) sev[i] = sep[(size_t)i * (16 * kH)];

    __syncthreads();                 // B1: wT + dshare staged, cell loads landed
    v2f dreg2[6];
#pragma unroll
    for (int rr = 0; rr < 6; ++rr) {
        dreg2[rr].x = dshare[(2 * rr) * kH + lane];      // stride-1: conflict-free
        dreg2[rr].y = dshare[(2 * rr + 1) * kH + lane];
    }
    // no B2: redbuf is a separate buffer, dshare is read-only hereafter

    float zreg[CELLS];
    zreg[0] = cell_z(relbase,            pfa0, pfb0, dreg2, sev[0], wz2);
    zreg[1] = cell_z(relbase + kRelCell, pfa1, pfb1, dreg2, sev[1], wz2);

    // epilogue: batched 64x64 matvec over 2 cells; lane = o
    float q0 = 0.f, q1 = 0.f;
#pragma unroll
    for (int d = 0; d < kH; ++d) {
        const float wv = wT[d * WT_LD + lane];
        q0 = fmaf(readlane_f(zreg[0], d), wv, q0);
        q1 = fmaf(readlane_f(zreg[1], d), wv, q1);
    }
    const float tot = fmaxf(q0 + ob, 0.f) + fmaxf(q1 + ob, 0.f);

    // block reduce -> one wave-atomic per block
    redbuf[w * 64 + lane] = tot;
    __syncthreads();                 // B3
    if (w == 0) {
        float r = 0.f;
#pragma unroll
        for (int j = 0; j < WAVES; ++j) r += redbuf[j * 64 + lane];
        atomicAdd(&out[bv * kNOUT + lane], r);
    }
}

extern "C" void kernel_launch(void* const* d_in, const int* in_sizes, int n_in,
                              void* d_out, int out_size, void* d_ws, size_t ws_size,
                              hipStream_t stream) {
    const float* rel   = (const float*)d_in[0];
    const float* sem   = (const float*)d_in[1];
    const float* s     = (const float*)d_in[2];
    const float* Wst   = (const float*)d_in[3];
    const float* lin_w = (const float*)d_in[4];
    const float* lin_b = (const float*)d_in[5];
    const float* out_w = (const float*)d_in[6];
    const float* out_b = (const float*)d_in[7];
    float* out = (float*)d_out;

    hipMemsetAsync(out, 0, sizeof(float) * 8 * 16 * kNOUT, stream);
    dim3 grid(2048), block(512);
    hipLaunchKernelGGL(gal_kernel, grid, block, 0, stream,
                       rel, sem, s, Wst, lin_w, lin_b, out_w, out_b, out);
}

// Round 24
// 42.515 us; speedup vs baseline: 1.1599x; 1.1599x over previous
//
#include <hip/hip_runtime.h>

namespace {
constexpr int kNP = 8, kNR = 12;
constexpr int kRelCell = 288;          // NP*K*NR floats per cell (1152 B)
constexpr int kH = 64, kNOUT = 64;
constexpr int CELLS = 2;               // cells per wave
constexpr int WAVES = 8;               // 512-thread blocks
constexpr int WT2_LD = 130;            // padded d-pair row: 2-way aliases only
}

typedef float v2f __attribute__((ext_vector_type(2)));

__device__ __forceinline__ float readlane_f(float v, int l) {
    union { float f; int i; } u; u.f = v;
    u.i = __builtin_amdgcn_readlane(u.i, l);
    return u.f;
}

// DPP add step on the VALU pipe; invalid source lanes contribute 0.
template<int CTRL>
__device__ __forceinline__ float dpp_add(float x) {
    int y = __builtin_amdgcn_update_dpp(0, __float_as_int(x), CTRL, 0xf, 0xf, true);
    return x + __int_as_float(y);
}
// 64-lane sum (no DS ops); lane 63 holds the total.
__device__ __forceinline__ float wave_sum63(float x) {
    x = dpp_add<0x111>(x);  // row_shr:1
    x = dpp_add<0x112>(x);  // row_shr:2
    x = dpp_add<0x114>(x);  // row_shr:4
    x = dpp_add<0x118>(x);  // row_shr:8
    x = dpp_add<0x142>(x);  // row_bcast:15
    x = dpp_add<0x143>(x);  // row_bcast:31
    return x;
}

// L2-warming prefetch of one 288-float cell: float4 covers floats 0..255,
// dword covers 224..287 -- complete, no OOB past the cell.
__device__ __forceinline__ void pf_issue(const float* cb, int lane,
                                         float4* a, float* b) {
    *a = *(const float4*)(cb + lane * 4);
    *b = cb[224 + lane];
}
// keep prefetch registers alive (placed AFTER the compute: waitcnt satisfied)
#define PF_SINK(a, b) asm volatile("" :: "v"((a).x), "v"((a).y), "v"((a).z), "v"((a).w), "v"(b))

// One cell's logits+softmax+combine; cb is wave-uniform -> scalar s_load path
// (packed v_pk_fma_f32 dots, r22 champion). wz2 pre-scaled by log2(e); raw
// v_exp_f32, no max subtraction, v_rcp vs precise divide (1 ulp, thr 0.2%).
__device__ __forceinline__ float cell_z(const float* __restrict__ cb,
                                        const v2f* __restrict__ dreg2,
                                        float sv_i, float wz2) {
    float zj[kNP], la[kNP];
#pragma unroll
    for (int p = 0; p < kNP; ++p) {
        const v2f* r2 = (const v2f*)(cb + p * 36);   // 18 wave-uniform float2
        v2f a0 = {0.f, 0.f}, a1 = {0.f, 0.f}, a2 = {0.f, 0.f};
#pragma unroll
        for (int rr = 0; rr < 6; ++rr) {
            a0 = __builtin_elementwise_fma(r2[rr],      dreg2[rr], a0);
            a1 = __builtin_elementwise_fma(r2[6 + rr],  dreg2[rr], a1);
            a2 = __builtin_elementwise_fma(r2[12 + rr], dreg2[rr], a2);
        }
        const float d0 = a0.x + a0.y;
        const float d1 = a1.x + a1.y;
        const float d2 = a2.x + a2.y;
        const float z = d0 * d1 * d2 * sv_i;
        zj[p] = z;
        la[p] = z * wz2;
    }
#pragma unroll
    for (int p = 0; p < kNP; ++p) la[p] = wave_sum63(la[p]);
    float esum = 0.f, zd = 0.f;
#pragma unroll
    for (int p = 0; p < kNP; ++p) {
        const float e = __builtin_amdgcn_exp2f(readlane_f(la[p], 63));
        esum += e;
        zd = fmaf(e, zj[p], zd);
    }
    return zd * __builtin_amdgcn_rcpf(esum);
}

// grid: 128 (b,v) x 16 f = 2048 blocks of 512 threads (8 waves); wave w ->
// t = 2w..2w+1 (r22 champion geometry/path). ONLY change: d-pair-packed
// epilogue -- wT stored as {w[o][2d2],w[o][2d2+1]} pairs (b64 reads, 2-way
// bank aliases = free), both cells accumulated with v_pk_fma_f32:
// 64x(b32+2rl+2fma)=320 -> 32x(b64+4rl+2pkfma)=224 instrs/wave.
__global__ __launch_bounds__(512, 4) void gal_kernel(
    const float* __restrict__ rel,      // (BS,NV,MF,MT,NP,K,NR)
    const float* __restrict__ se,       // (BS,NV,MT,MF,H)
    const float* __restrict__ s,        // unused (cancels in softmax)
    const float* __restrict__ Wstack,   // (NR,H,H)
    const float* __restrict__ lin_w,    // (1,H+NOUT)
    const float* __restrict__ lin_b,    // unused (cancels)
    const float* __restrict__ out_w,    // (NOUT,H)
    const float* __restrict__ out_b,    // (NOUT,)
    float* __restrict__ out)            // (BS,NV,NOUT)
{
    __shared__ __align__(16) float wT2[32 * WT2_LD];   // 16.25 KB (d-pair layout)
    __shared__ __align__(16) float dshare[kNR * kH];   // 3 KB diag; reused as redbuf

    const int tid  = (int)threadIdx.x;
    const int lane = tid & 63;
    const int w    = __builtin_amdgcn_readfirstlane(tid >> 6);  // uniform wave id 0..7

    const int bv = (int)blockIdx.x >> 4;   // 0..127
    const int f  = (int)blockIdx.x & 15;
    const int t0 = w * CELLS;

    const float* relbase = rel + ((size_t)((bv * 16 + f) * 16) + t0) * kRelCell;

    // prefetch both cells immediately (warm L2 for the scalar loads)
    float4 pfa0, pfa1; float pfb0, pfb1;
    pf_issue(relbase,            lane, &pfa0, &pfb0);
    pf_issue(relbase + kRelCell, lane, &pfa1, &pfb1);

    // out_w (o,d) -> wT2[(d>>1)*130 + o*2 + (d&1)]: coalesced global read;
    // LDS writes 2-way bank-aliased (free per m136)
    for (int i = tid; i < kH * kNOUT; i += 512) {
        const int o = i >> 6, d = i & 63;
        wT2[(d >> 1) * WT2_LD + o * 2 + (d & 1)] = out_w[i];
    }
    // diag gather (stride-65 in Wstack) once per block
    for (int i = tid; i < kNR * kH; i += 512) {
        const int r = i >> 6, d = i & 63;
        dshare[i] = Wstack[r * kH * kH + d * (kH + 1)];
    }

    const float wz2 = lin_w[kNOUT + lane] * 1.44269504088896340736f;  // log2(e)
    const float ob = out_b[lane];   // lane = o in epilogue
    const float* sep = se + ((size_t)(bv * 16 + t0) * 16 + f) * kH + lane;
    float sev[CELLS];
#pragma unroll
    for (int i = 0; i < CELLS; ++i) sev[i] = sep[(size_t)i * (16 * kH)];

    __syncthreads();                 // B1: wT2 + dshare staged (+ prefetch drained)
    v2f dreg2[6];
#pragma unroll
    for (int rr = 0; rr < 6; ++rr) {
        dreg2[rr].x = dshare[(2 * rr) * kH + lane];      // stride-1: conflict-free
        dreg2[rr].y = dshare[(2 * rr + 1) * kH + lane];
    }
    __syncthreads();                 // B2: diag consumed -> dshare free for redbuf

    float zreg[CELLS];
    zreg[0] = cell_z(relbase,            dreg2, sev[0], wz2);
    PF_SINK(pfa0, pfb0);
    zreg[1] = cell_z(relbase + kRelCell, dreg2, sev[1], wz2);
    PF_SINK(pfa1, pfb1);

    // epilogue: d-pair packed 64x64 matvec over 2 cells; lane = o
    v2f Q0 = {0.f, 0.f}, Q1 = {0.f, 0.f};
#pragma unroll
    for (int d2 = 0; d2 < 32; ++d2) {
        const v2f wv = *(const v2f*)&wT2[d2 * WT2_LD + lane * 2];  // b64, 2-way alias
        v2f zz0, zz1;
        zz0.x = readlane_f(zreg[0], 2 * d2);
        zz0.y = readlane_f(zreg[0], 2 * d2 + 1);
        zz1.x = readlane_f(zreg[1], 2 * d2);
        zz1.y = readlane_f(zreg[1], 2 * d2 + 1);
        Q0 = __builtin_elementwise_fma(wv, zz0, Q0);
        Q1 = __builtin_elementwise_fma(wv, zz1, Q1);
    }
    const float q0 = Q0.x + Q0.y, q1 = Q1.x + Q1.y;
    const float tot = fmaxf(q0 + ob, 0.f) + fmaxf(q1 + ob, 0.f);

    // block reduce (dshare[0..511] reused) -> one wave-atomic per block
    dshare[w * 64 + lane] = tot;
    __syncthreads();                 // B3
    if (w == 0) {
        float r = 0.f;
#pragma unroll
        for (int j = 0; j < WAVES; ++j) r += dshare[j * 64 + lane];
        atomicAdd(&out[bv * kNOUT + lane], r);
    }
}

extern "C" void kernel_launch(void* const* d_in, const int* in_sizes, int n_in,
                              void* d_out, int out_size, void* d_ws, size_t ws_size,
                              hipStream_t stream) {
    const float* rel   = (const float*)d_in[0];
    const float* sem   = (const float*)d_in[1];
    const float* s     = (const float*)d_in[2];
    const float* Wst   = (const float*)d_in[3];
    const float* lin_w = (const float*)d_in[4];
    const float* lin_b = (const float*)d_in[5];
    const float* out_w = (const float*)d_in[6];
    const float* out_b = (const float*)d_in[7];
    float* out = (float*)d_out;

    hipMemsetAsync(out, 0, sizeof(float) * 8 * 16 * kNOUT, stream);
    dim3 grid(2048), block(512);
    hipLaunchKernelGGL(gal_kernel, grid, block, 0, stream,
                       rel, sem, s, Wst, lin_w, lin_b, out_w, out_b, out);
}